// Round 1
// 87.764 us; speedup vs baseline: 1.0047x; 1.0047x over previous
//
#include <hip/hip_runtime.h>
#include <hip/hip_fp16.h>
#include <stdint.h>

#define IN_F    4096
#define OUT_F   11008
#define NBITS   4
#define GROUP   128
#define NGROUPS 32
#define NWORDS  128

typedef _Float16 half2_t __attribute__((ext_vector_type(2)));

union U32H2 { uint32_t u; half2_t h; };

// WG = 1 wave (64 threads) = 1 group x 128 outputs (2 per lane, dwordx2 loads).
// grid = (OUT_F/128, NGROUPS) = 86 x 32 = 2752 WGs -> 10.75 waves/CU.
// ATOMIC=false: per-(g,o) partials stored to ws[g][o] (coalesced float2, no
// contention); a second tiny kernel reduces over g. ATOMIC=true is the old
// 32-contender atomicAdd path, kept only as a ws_size fallback.
template<bool ATOMIC>
__global__ __launch_bounds__(64)
void lutgemm_kernel(const float* __restrict__ x,
                    const int*   __restrict__ qweight,
                    const float* __restrict__ alpha,
                    const float* __restrict__ qbias,
                    float*       __restrict__ out)   // ATOMIC ? y : ws
{
    // 4 words (this group's) x 16 interleaved f16 pairs (x[32w+k], x[32w+k+16])
    __shared__ uint32_t sx[64];

    const int lane = threadIdx.x;               // 0..63
    const int g    = blockIdx.y;                // group 0..31
    const int o2   = blockIdx.x * 128 + lane * 2;  // this thread: outputs o2, o2+1

    // ---- issue all global loads early: 16 x dwordx2 sign-masks (+ alpha/qbias) ----
    uint2 m[4][4];                              // .x -> o2, .y -> o2+1
    const int gw0 = g * 4;
#pragma unroll
    for (int wi = 0; wi < 4; ++wi)
#pragma unroll
        for (int b = 0; b < NBITS; ++b)
            m[wi][b] = *(const uint2*)&qweight[(size_t)((gw0 + wi) * NBITS + b) * OUT_F + o2];

    float2 a[NBITS];
#pragma unroll
    for (int b = 0; b < NBITS; ++b)
        a[b] = *(const float2*)&alpha[(size_t)(g * NBITS + b) * OUT_F + o2];
    const float2 qb = *(const float2*)&qbias[(size_t)g * OUT_F + o2];

    // ---- exact f32 group sum S_g = sum_{i in g} x[i] (for the q_bias term) ----
    float2 x2 = ((const float2*)x)[g * 64 + lane];
    float sg = x2.x + x2.y;
#pragma unroll
    for (int off = 32; off > 0; off >>= 1)
        sg += __shfl_xor(sg, off, 64);

    // ---- LDS prep: one interleaved f16 pair per thread (4 words x 16 pairs) ----
    {
        const int widx = lane >> 4;             // word within group, 0..3
        const int k    = lane & 15;             // pair index, 0..15
        const int gw   = gw0 + widx;
        U32H2 u;
        u.h[0] = (_Float16)x[gw * 32 + k];
        u.h[1] = (_Float16)x[gw * 32 + k + 16];
        sx[lane] = u.u;
    }
    __syncthreads();

    // ---- main: per (wi,b,k): 2 shifts + 2 and_or + 2 dot2 for 4 MACs (2 outs) ----
    float p0[NBITS] = {0.f, 0.f, 0.f, 0.f};
    float p1[NBITS] = {0.f, 0.f, 0.f, 0.f};
#pragma unroll
    for (int wi = 0; wi < 4; ++wi) {
        const uint4* sp = (const uint4*)&sx[wi * 16];  // wave-uniform -> LDS broadcast
        uint4 v0 = sp[0], v1 = sp[1], v2 = sp[2], v3 = sp[3];
#pragma unroll
        for (int b = 0; b < NBITS; ++b) {
            const uint32_t mm0 = m[wi][b].x;
            const uint32_t mm1 = m[wi][b].y;
#define STEP(K, XW)                                                          \
            {                                                                \
                uint32_t t0 = mm0 << (15 - (K));                             \
                uint32_t t1 = mm1 << (15 - (K));                             \
                U32H2 s0; s0.u = (t0 & 0x80008000u) | 0x3C003C00u;           \
                U32H2 s1; s1.u = (t1 & 0x80008000u) | 0x3C003C00u;           \
                U32H2 xp; xp.u = (XW);                                       \
                p0[b] = __builtin_amdgcn_fdot2(s0.h, xp.h, p0[b], false);    \
                p1[b] = __builtin_amdgcn_fdot2(s1.h, xp.h, p1[b], false);    \
            }
            STEP(0,  v0.x) STEP(1,  v0.y) STEP(2,  v0.z) STEP(3,  v0.w)
            STEP(4,  v1.x) STEP(5,  v1.y) STEP(6,  v1.z) STEP(7,  v1.w)
            STEP(8,  v2.x) STEP(9,  v2.y) STEP(10, v2.z) STEP(11, v2.w)
            STEP(12, v3.x) STEP(13, v3.y) STEP(14, v3.z) STEP(15, v3.w)
#undef STEP
        }
    }

    // p = -partial (bit=1 -> -1 convention), so y += sum_b alpha * (-p) + qb * S_g
    float yc0 = qb.x * sg;
    float yc1 = qb.y * sg;
#pragma unroll
    for (int b = 0; b < NBITS; ++b) {
        yc0 = __builtin_fmaf(-a[b].x, p0[b], yc0);
        yc1 = __builtin_fmaf(-a[b].y, p1[b], yc1);
    }

    if (ATOMIC) {
        unsafeAtomicAdd(&out[o2],     yc0);
        unsafeAtomicAdd(&out[o2 + 1], yc1);
    } else {
        float2 r; r.x = yc0; r.y = yc1;
        *(float2*)&out[(size_t)g * OUT_F + o2] = r;   // coalesced, contention-free
    }
}

// y[o] = sum_g ws[g][o].  11008 = 43 * 256 exactly.
// 172 waves; 32 coalesced loads per thread (256 B/wave per g), all issued
// before the adds so the single vmcnt wait covers the L2-hot round trip.
__global__ __launch_bounds__(256)
void reduce_groups(const float* __restrict__ ws, float* __restrict__ y)
{
    const int o = blockIdx.x * 256 + threadIdx.x;
    float s0 = 0.f, s1 = 0.f, s2 = 0.f, s3 = 0.f;
#pragma unroll
    for (int g = 0; g < NGROUPS; g += 4) {
        s0 += ws[(size_t)(g + 0) * OUT_F + o];
        s1 += ws[(size_t)(g + 1) * OUT_F + o];
        s2 += ws[(size_t)(g + 2) * OUT_F + o];
        s3 += ws[(size_t)(g + 3) * OUT_F + o];
    }
    y[o] = (s0 + s1) + (s2 + s3);
}

extern "C" void kernel_launch(void* const* d_in, const int* in_sizes, int n_in,
                              void* d_out, int out_size, void* d_ws, size_t ws_size,
                              hipStream_t stream) {
    const float* x     = (const float*)d_in[0];
    const int*   qw    = (const int*)d_in[1];
    const float* alpha = (const float*)d_in[2];
    const float* qbias = (const float*)d_in[3];
    float*       y     = (float*)d_out;

    const size_t ws_needed = (size_t)NGROUPS * OUT_F * sizeof(float);  // 1.41 MB
    dim3 grid(OUT_F / 128, NGROUPS);

    if (ws_size >= ws_needed && d_ws != nullptr) {
        float* ws = (float*)d_ws;
        lutgemm_kernel<false><<<grid, 64, 0, stream>>>(x, qw, alpha, qbias, ws);
        reduce_groups<<<dim3(OUT_F / 256), 256, 0, stream>>>(ws, y);
    } else {
        // fallback: old atomic path
        hipMemsetAsync(y, 0, OUT_F * sizeof(float), stream);
        lutgemm_kernel<true><<<grid, 64, 0, stream>>>(x, qw, alpha, qbias, y);
    }
}

// Round 2
// 86.591 us; speedup vs baseline: 1.0183x; 1.0136x over previous
//
#include <hip/hip_runtime.h>
#include <hip/hip_fp16.h>
#include <stdint.h>

#define IN_F    4096
#define OUT_F   11008
#define NBITS   4
#define GROUP   128
#define NGROUPS 32
#define NWORDS  128

typedef _Float16 half2_t __attribute__((ext_vector_type(2)));

union U32H2 { uint32_t u; half2_t h; };

// Fused single-pass version.
// WG = 256 threads = 4 waves; wave w handles group g = blockIdx.y*4 + w for
// outputs [blockIdx.x*128, +128) (2 per lane, dwordx2 mask loads).
// grid = (86, 8) = 688 WGs -> 2752 waves (same as before), 10.75 waves/CU.
// Cross-wave combine in LDS, then ONE 8-contender atomicAdd pair per output
// (round 1 proved even 32-contender atomics cost ~nothing).
__global__ __launch_bounds__(256)
void lutgemm_fused(const float* __restrict__ x,
                   const int*   __restrict__ qweight,
                   const float* __restrict__ alpha,
                   const float* __restrict__ qbias,
                   float*       __restrict__ y)
{
    // per-wave: 4 words (this group's) x 16 interleaved f16 pairs
    __shared__ uint32_t sx[4][64];
    __shared__ float2   red[4][64];

    const int tid  = threadIdx.x;
    const int lane = tid & 63;
    const int w    = tid >> 6;                  // wave 0..3
    const int g    = blockIdx.y * 4 + w;        // group 0..31
    const int o2   = blockIdx.x * 128 + lane * 2;

    // ---- issue all global loads early: 16 x dwordx2 sign-masks (+ alpha/qbias) ----
    uint2 m[4][4];                              // .x -> o2, .y -> o2+1
    const int gw0 = g * 4;
#pragma unroll
    for (int wi = 0; wi < 4; ++wi)
#pragma unroll
        for (int b = 0; b < NBITS; ++b)
            m[wi][b] = *(const uint2*)&qweight[(size_t)((gw0 + wi) * NBITS + b) * OUT_F + o2];

    float2 a[NBITS];
#pragma unroll
    for (int b = 0; b < NBITS; ++b)
        a[b] = *(const float2*)&alpha[(size_t)(g * NBITS + b) * OUT_F + o2];
    const float2 qb = *(const float2*)&qbias[(size_t)g * OUT_F + o2];

    // ---- exact f32 group sum S_g = sum_{i in g} x[i] (for the q_bias term) ----
    float2 x2 = ((const float2*)x)[g * 64 + lane];
    float sg = x2.x + x2.y;
#pragma unroll
    for (int off = 32; off > 0; off >>= 1)
        sg += __shfl_xor(sg, off, 64);

    // ---- LDS prep: one interleaved f16 pair per thread (4 words x 16 pairs) ----
    {
        const int widx = lane >> 4;             // word within group, 0..3
        const int k    = lane & 15;             // pair index, 0..15
        const int gw   = gw0 + widx;
        U32H2 u;
        u.h[0] = (_Float16)x[gw * 32 + k];
        u.h[1] = (_Float16)x[gw * 32 + k + 16];
        sx[w][lane] = u.u;
    }
    __syncthreads();

    // ---- main: per (wi,b,k): 2 shifts + 2 and_or + 2 dot2 for 4 MACs (2 outs) ----
    float p0[NBITS] = {0.f, 0.f, 0.f, 0.f};
    float p1[NBITS] = {0.f, 0.f, 0.f, 0.f};
#pragma unroll
    for (int wi = 0; wi < 4; ++wi) {
        const uint4* sp = (const uint4*)&sx[w][wi * 16];  // wave-uniform -> LDS broadcast
        uint4 v0 = sp[0], v1 = sp[1], v2 = sp[2], v3 = sp[3];
#pragma unroll
        for (int b = 0; b < NBITS; ++b) {
            const uint32_t mm0 = m[wi][b].x;
            const uint32_t mm1 = m[wi][b].y;
#define STEP(K, XW)                                                          \
            {                                                                \
                uint32_t t0 = mm0 << (15 - (K));                             \
                uint32_t t1 = mm1 << (15 - (K));                             \
                U32H2 s0; s0.u = (t0 & 0x80008000u) | 0x3C003C00u;           \
                U32H2 s1; s1.u = (t1 & 0x80008000u) | 0x3C003C00u;           \
                U32H2 xp; xp.u = (XW);                                       \
                p0[b] = __builtin_amdgcn_fdot2(s0.h, xp.h, p0[b], false);    \
                p1[b] = __builtin_amdgcn_fdot2(s1.h, xp.h, p1[b], false);    \
            }
            STEP(0,  v0.x) STEP(1,  v0.y) STEP(2,  v0.z) STEP(3,  v0.w)
            STEP(4,  v1.x) STEP(5,  v1.y) STEP(6,  v1.z) STEP(7,  v1.w)
            STEP(8,  v2.x) STEP(9,  v2.y) STEP(10, v2.z) STEP(11, v2.w)
            STEP(12, v3.x) STEP(13, v3.y) STEP(14, v3.z) STEP(15, v3.w)
#undef STEP
        }
    }

    // p = -partial (bit=1 -> -1 convention), so y += sum_b alpha * (-p) + qb * S_g
    float yc0 = qb.x * sg;
    float yc1 = qb.y * sg;
#pragma unroll
    for (int b = 0; b < NBITS; ++b) {
        yc0 = __builtin_fmaf(-a[b].x, p0[b], yc0);
        yc1 = __builtin_fmaf(-a[b].y, p1[b], yc1);
    }

    // ---- cross-wave combine (4 partials) + 8-contender atomic to y ----
    float2 r; r.x = yc0; r.y = yc1;
    red[w][lane] = r;
    __syncthreads();
    if (w == 0) {
        float2 r0 = red[0][lane], r1 = red[1][lane],
               r2 = red[2][lane], r3 = red[3][lane];
        unsafeAtomicAdd(&y[o2],     (r0.x + r1.x) + (r2.x + r3.x));
        unsafeAtomicAdd(&y[o2 + 1], (r0.y + r1.y) + (r2.y + r3.y));
    }
}

extern "C" void kernel_launch(void* const* d_in, const int* in_sizes, int n_in,
                              void* d_out, int out_size, void* d_ws, size_t ws_size,
                              hipStream_t stream) {
    const float* x     = (const float*)d_in[0];
    const int*   qw    = (const int*)d_in[1];
    const float* alpha = (const float*)d_in[2];
    const float* qbias = (const float*)d_in[3];
    float*       y     = (float*)d_out;

    hipMemsetAsync(y, 0, OUT_F * sizeof(float), stream);
    lutgemm_fused<<<dim3(OUT_F / 128, NGROUPS / 4), 256, 0, stream>>>(
        x, qw, alpha, qbias, y);
}